// Round 2
// baseline (1385.865 us; speedup 1.0000x reference)
//
#include <hip/hip_runtime.h>
#include <math.h>

#define N_NODES 50000
#define N_EDGES 800000
#define ND 128
#define ED 16
#define H1 256
#define H2 32
#define NEG_SLOPE 0.2f

// ---------------------------------------------------------------- degree counts
__global__ void k_deg(const int* __restrict__ ei, int* __restrict__ counts, int E) {
    int e = blockIdx.x * blockDim.x + threadIdx.x;
    if (e < E) atomicAdd(&counts[ei[E + e]], 1);
}

// ---------------------------------------------------------------- 3-phase scan -> rowptr (rowptr[i+1] incl, +1 self loop each)
__global__ void k_scan1(const int* __restrict__ counts, int* __restrict__ partial, int n, int chunk) {
    __shared__ int sh[256];
    int beg = blockIdx.x * chunk, end = min(beg + chunk, n);
    int sum = 0;
    for (int i = beg + threadIdx.x; i < end; i += 256) sum += counts[i] + 1;
    sh[threadIdx.x] = sum;
    __syncthreads();
    for (int off = 128; off; off >>= 1) {
        if (threadIdx.x < off) sh[threadIdx.x] += sh[threadIdx.x + off];
        __syncthreads();
    }
    if (threadIdx.x == 0) partial[blockIdx.x] = sh[0];
}
__global__ void k_scan2(int* __restrict__ partial) {  // 1 block, 256 threads, exclusive in place
    __shared__ int sh[256];
    int v = partial[threadIdx.x];
    sh[threadIdx.x] = v;
    __syncthreads();
    for (int off = 1; off < 256; off <<= 1) {
        int t = (threadIdx.x >= off) ? sh[threadIdx.x - off] : 0;
        __syncthreads();
        sh[threadIdx.x] += t;
        __syncthreads();
    }
    partial[threadIdx.x] = sh[threadIdx.x] - v;
}
__global__ void k_scan3(const int* __restrict__ counts, const int* __restrict__ partial,
                        int* __restrict__ rowptr, int n, int chunk) {
    __shared__ int sh[256];
    int beg = blockIdx.x * chunk, end = min(beg + chunk, n);
    int run = partial[blockIdx.x];
    for (int base = beg; base < end; base += 256) {
        int i = base + threadIdx.x;
        int v = (i < end) ? counts[i] + 1 : 0;
        sh[threadIdx.x] = v;
        __syncthreads();
        for (int off = 1; off < 256; off <<= 1) {
            int t = (threadIdx.x >= off) ? sh[threadIdx.x - off] : 0;
            __syncthreads();
            sh[threadIdx.x] += t;
            __syncthreads();
        }
        if (i < end) rowptr[i + 1] = run + sh[threadIdx.x];
        __syncthreads();
        run += sh[255];
        __syncthreads();
    }
    if (blockIdx.x == 0 && threadIdx.x == 0) rowptr[0] = 0;
}

// ---------------------------------------------------------------- fill CSR (src, dst, eid); self loop in last slot
__global__ void k_fill_csr(const int* __restrict__ ei, const int* __restrict__ rowptr,
                           int* __restrict__ fill, int* __restrict__ csr_src,
                           int* __restrict__ csr_dst, int* __restrict__ csr_eid, int E, int n) {
    int idx = blockIdx.x * blockDim.x + threadIdx.x;
    if (idx < E) {
        int dst = ei[E + idx];
        int slot = rowptr[dst] + atomicAdd(&fill[dst], 1);
        csr_src[slot] = ei[idx];
        csr_dst[slot] = dst;
        csr_eid[slot] = idx;
    } else if (idx < E + n) {
        int i = idx - E;
        int slot = rowptr[i + 1] - 1;
        csr_src[slot] = i;
        csr_dst[slot] = i;
        csr_eid[slot] = E + i;
    }
}

// ---------------------------------------------------------------- loop_attr from CSR (no atomics)
__global__ void k_loop_attr(const float* __restrict__ ea, const int* __restrict__ rowptr,
                            const int* __restrict__ csr_eid, float* __restrict__ loop_attr, int n, int E) {
    int idx = blockIdx.x * blockDim.x + threadIdx.x;
    if (idx >= n * ED) return;
    int node = idx >> 4, d = idx & 15;
    int beg = rowptr[node], end = rowptr[node + 1] - 1;  // exclude self-loop slot
    float sum = 0.f;
    for (int j = beg; j < end; ++j) sum += ea[(size_t)csr_eid[j] * ED + d];
    int cnt = end - beg;
    loop_attr[idx] = sum / (float)(cnt > 0 ? cnt : 1);
}

// ---------------------------------------------------------------- GEMM: Y[n][C] = X[n][K] @ W[C][K]^T + b
#define GT 64
#define GK 32
__global__ __launch_bounds__(256) void k_gemm_xwt(const float* __restrict__ X,
                                                  const float* __restrict__ W,
                                                  const float* __restrict__ bias,
                                                  float* __restrict__ Y,
                                                  int n, int K, int C) {
    __shared__ float xs[GT][GK + 1];
    __shared__ float ws[GT][GK + 1];
    int tid = threadIdx.x;
    int tx = tid & 15, ty = tid >> 4;
    int row0 = blockIdx.x * GT, col0 = blockIdx.y * GT;
    float acc[4][4] = {};
    for (int k0 = 0; k0 < K; k0 += GK) {
        #pragma unroll
        for (int l = 0; l < (GT * GK) / 256; ++l) {
            int idx = l * 256 + tid;
            int r = idx >> 5, kk = idx & 31;
            int gr = row0 + r;
            xs[r][kk] = (gr < n) ? X[(size_t)gr * K + k0 + kk] : 0.f;
            int gc = col0 + r;
            ws[r][kk] = (gc < C) ? W[(size_t)gc * K + k0 + kk] : 0.f;
        }
        __syncthreads();
        #pragma unroll
        for (int kk = 0; kk < GK; ++kk) {
            float a[4], b[4];
            #pragma unroll
            for (int i = 0; i < 4; ++i) a[i] = xs[ty * 4 + i][kk];
            #pragma unroll
            for (int j = 0; j < 4; ++j) b[j] = ws[tx * 4 + j][kk];
            #pragma unroll
            for (int i = 0; i < 4; ++i)
                #pragma unroll
                for (int j = 0; j < 4; ++j) acc[i][j] += a[i] * b[j];
        }
        __syncthreads();
    }
    #pragma unroll
    for (int i = 0; i < 4; ++i) {
        int r = row0 + ty * 4 + i;
        if (r >= n) continue;
        #pragma unroll
        for (int j = 0; j < 4; ++j) {
            int c = col0 + tx * 4 + j;
            if (c < C) Y[(size_t)r * C + c] = acc[i][j] + bias[c];
        }
    }
}

// ---------------------------------------------------------------- layer-1 logits: one wave per CSR slot (contiguous chunks)
__global__ __launch_bounds__(256) void k_logits1(const float* __restrict__ xl,
                                                 const float* __restrict__ xr,
                                                 const float* __restrict__ edge_attr,
                                                 const float* __restrict__ loop_attr,
                                                 const float* __restrict__ We,
                                                 const float* __restrict__ att,
                                                 const int* __restrict__ csr_src,
                                                 const int* __restrict__ csr_dst,
                                                 const int* __restrict__ csr_eid,
                                                 float* __restrict__ logit, int total, int E) {
    int wave = (blockIdx.x * blockDim.x + threadIdx.x) >> 6;
    int lane = threadIdx.x & 63;
    int n_waves = (gridDim.x * blockDim.x) >> 6;
    int chunk = (total + n_waves - 1) / n_waves;
    int wbeg = wave * chunk, wend = min(wbeg + chunk, total);

    // lane owns channels lane*4 .. lane*4+3
    float4 w[4][4];
    #pragma unroll
    for (int r = 0; r < 4; ++r)
        #pragma unroll
        for (int q = 0; q < 4; ++q) w[r][q] = ((const float4*)We)[(lane * 4 + r) * 4 + q];
    float4 attv = ((const float4*)att)[lane];

    for (int j = wbeg; j < wend; ++j) {
        int s = csr_src[j], d = csr_dst[j], e = csr_eid[j];
        const float* eap = (e < E) ? edge_attr + (size_t)e * ED : loop_attr + (size_t)(e - E) * ED;
        float4 ea0 = ((const float4*)eap)[0];
        float4 ea1 = ((const float4*)eap)[1];
        float4 ea2 = ((const float4*)eap)[2];
        float4 ea3 = ((const float4*)eap)[3];
        float4 xlv = *(const float4*)(xl + (size_t)s * H1 + lane * 4);
        float4 xrv = *(const float4*)(xr + (size_t)d * H1 + lane * 4);
        float p = 0.f;
        #pragma unroll
        for (int r = 0; r < 4; ++r) {
            float we = w[r][0].x * ea0.x + w[r][0].y * ea0.y + w[r][0].z * ea0.z + w[r][0].w * ea0.w
                     + w[r][1].x * ea1.x + w[r][1].y * ea1.y + w[r][1].z * ea1.z + w[r][1].w * ea1.w
                     + w[r][2].x * ea2.x + w[r][2].y * ea2.y + w[r][2].z * ea2.z + w[r][2].w * ea2.w
                     + w[r][3].x * ea3.x + w[r][3].y * ea3.y + w[r][3].z * ea3.z + w[r][3].w * ea3.w;
            float t = ((const float*)&xlv)[r] + ((const float*)&xrv)[r] + we;
            t = (t > 0.f) ? t : NEG_SLOPE * t;
            p += ((const float*)&attv)[r] * t;
        }
        #pragma unroll
        for (int off = 32; off >= 1; off >>= 1) p += __shfl_xor(p, off);
        if (lane == 0) logit[j] = p;
    }
}

// ---------------------------------------------------------------- layer-1 aggregate: one block per node, no barriers
__global__ __launch_bounds__(256) void k_agg1(const float* __restrict__ xl,
                                              const float* __restrict__ logit,
                                              const int* __restrict__ rowptr,
                                              const int* __restrict__ csr_src,
                                              const float* __restrict__ bias,
                                              float* __restrict__ out) {
    int node = blockIdx.x;
    int c = threadIdx.x;
    int beg = rowptr[node], end = rowptr[node + 1];
    float m = -1e30f;
    for (int j = beg; j < end; ++j) m = fmaxf(m, logit[j]);
    float denom = 0.f, acc = 0.f;
    for (int j = beg; j < end; ++j) {
        float pe = __expf(logit[j] - m);
        int s = csr_src[j];
        denom += pe;
        acc += pe * xl[(size_t)s * H1 + c];
    }
    out[(size_t)node * H1 + c] = acc / denom + bias[c];
}

// ---------------------------------------------------------------- layer-2 logits: half-wave per slot
__global__ __launch_bounds__(256) void k_logits2(const float* __restrict__ xl,
                                                 const float* __restrict__ xr,
                                                 const float* __restrict__ edge_attr,
                                                 const float* __restrict__ loop_attr,
                                                 const float* __restrict__ We,
                                                 const float* __restrict__ att,
                                                 const int* __restrict__ csr_src,
                                                 const int* __restrict__ csr_dst,
                                                 const int* __restrict__ csr_eid,
                                                 float* __restrict__ logit, int total, int E) {
    int wave = (blockIdx.x * blockDim.x + threadIdx.x) >> 6;
    int lane = threadIdx.x & 63;
    int sub = lane >> 5, c = lane & 31;
    int n_waves = (gridDim.x * blockDim.x) >> 6;
    int chunk = ((total + n_waves - 1) / n_waves + 1) & ~1;
    int wbeg = wave * chunk, wend = min(wbeg + chunk, total);

    float4 w0 = ((const float4*)We)[c * 4 + 0];
    float4 w1 = ((const float4*)We)[c * 4 + 1];
    float4 w2 = ((const float4*)We)[c * 4 + 2];
    float4 w3 = ((const float4*)We)[c * 4 + 3];
    float attc = att[c];

    for (int base = wbeg; base < wend; base += 2) {
        int j = base + sub;
        if (j < wend) {
            int s = csr_src[j], d = csr_dst[j], e = csr_eid[j];
            const float* eap = (e < E) ? edge_attr + (size_t)e * ED : loop_attr + (size_t)(e - E) * ED;
            float4 ea0 = ((const float4*)eap)[0];
            float4 ea1 = ((const float4*)eap)[1];
            float4 ea2 = ((const float4*)eap)[2];
            float4 ea3 = ((const float4*)eap)[3];
            float we = w0.x * ea0.x + w0.y * ea0.y + w0.z * ea0.z + w0.w * ea0.w
                     + w1.x * ea1.x + w1.y * ea1.y + w1.z * ea1.z + w1.w * ea1.w
                     + w2.x * ea2.x + w2.y * ea2.y + w2.z * ea2.z + w2.w * ea2.w
                     + w3.x * ea3.x + w3.y * ea3.y + w3.z * ea3.z + w3.w * ea3.w;
            float t = xl[(size_t)s * H2 + c] + xr[(size_t)d * H2 + c] + we;
            t = (t > 0.f) ? t : NEG_SLOPE * t;
            float p = attc * t;
            #pragma unroll
            for (int off = 16; off >= 1; off >>= 1) p += __shfl_xor(p, off);
            if (c == 0) logit[j] = p;
        }
    }
}

// ---------------------------------------------------------------- layer-2 aggregate: 32-lane group per node
__global__ __launch_bounds__(256) void k_agg2(const float* __restrict__ xl,
                                              const float* __restrict__ logit,
                                              const int* __restrict__ rowptr,
                                              const int* __restrict__ csr_src,
                                              const float* __restrict__ bias,
                                              float* __restrict__ out, int n) {
    int g = threadIdx.x >> 5, c = threadIdx.x & 31;
    int node = blockIdx.x * 8 + g;
    if (node >= n) return;
    int beg = rowptr[node], end = rowptr[node + 1];
    float m = -1e30f;
    for (int j = beg; j < end; ++j) m = fmaxf(m, logit[j]);
    float denom = 0.f, acc = 0.f;
    for (int j = beg; j < end; ++j) {
        float pe = __expf(logit[j] - m);
        int s = csr_src[j];
        denom += pe;
        acc += pe * xl[(size_t)s * H2 + c];
    }
    out[(size_t)node * H2 + c] = acc / denom + bias[c];
}

// ---------------------------------------------------------------- mean over nodes
__global__ __launch_bounds__(256) void k_mean(const float* __restrict__ h2,
                                              float* __restrict__ out, int total, float invN) {
    __shared__ float red[H2];
    int tid = threadIdx.x;
    if (tid < H2) red[tid] = 0.f;
    __syncthreads();
    float part = 0.f;
    for (int idx = blockIdx.x * blockDim.x + tid; idx < total; idx += gridDim.x * blockDim.x)
        part += h2[idx];
    atomicAdd(&red[tid & 31], part);
    __syncthreads();
    if (tid < H2) atomicAdd(&out[tid], red[tid] * invN);
}

// ----------------------------------------------------------------
extern "C" void kernel_launch(void* const* d_in, const int* in_sizes, int n_in,
                              void* d_out, int out_size, void* d_ws, size_t ws_size,
                              hipStream_t stream) {
    const float* x   = (const float*)d_in[0];
    const int*   ei  = (const int*)d_in[1];
    const float* ea  = (const float*)d_in[2];
    const float* Wl1 = (const float*)d_in[3];
    const float* bl1 = (const float*)d_in[4];
    const float* Wr1 = (const float*)d_in[5];
    const float* br1 = (const float*)d_in[6];
    const float* We1 = (const float*)d_in[7];
    const float* at1 = (const float*)d_in[8];
    const float* bi1 = (const float*)d_in[9];
    const float* Wl2 = (const float*)d_in[10];
    const float* bl2 = (const float*)d_in[11];
    const float* Wr2 = (const float*)d_in[12];
    const float* br2 = (const float*)d_in[13];
    const float* We2 = (const float*)d_in[14];
    const float* at2 = (const float*)d_in[15];
    const float* bi2 = (const float*)d_in[16];
    float* out = (float*)d_out;

    const int N = N_NODES, E = N_EDGES, ET = N_EDGES + N_NODES;
    const int SCAN_CHUNK = (N + 255) / 256;  // 196

    size_t off = 0;
    auto carve = [&](size_t bytes) {
        void* p = (char*)d_ws + off;
        off += (bytes + 255) & ~(size_t)255;
        return p;
    };
    int*   counts    = (int*)carve((size_t)N * 4);
    int*   fill      = (int*)carve((size_t)N * 4);
    int*   rowptr    = (int*)carve((size_t)(N + 1) * 4);
    int*   partial   = (int*)carve(256 * 4);
    float* loop_attr = (float*)carve((size_t)N * ED * 4);
    int*   csr_src   = (int*)carve((size_t)ET * 4);
    int*   csr_dst   = (int*)carve((size_t)ET * 4);
    int*   csr_eid   = (int*)carve((size_t)ET * 4);
    float* logit     = (float*)carve((size_t)ET * 4);
    float* xl1       = (float*)carve((size_t)N * H1 * 4);
    float* xr1       = (float*)carve((size_t)N * H1 * 4);
    float* h1        = (float*)carve((size_t)N * H1 * 4);
    // layer-2 buffers alias xr1 (free after k_logits1)
    float* xl2 = xr1;
    float* xr2 = xr1 + (size_t)N * H2;
    float* h2  = xr1 + 2 * (size_t)N * H2;

    hipMemsetAsync(counts, 0, (size_t)N * 4, stream);
    hipMemsetAsync(fill, 0, (size_t)N * 4, stream);
    hipMemsetAsync(out, 0, (size_t)H2 * 4, stream);

    k_deg<<<(E + 255) / 256, 256, 0, stream>>>(ei, counts, E);
    k_scan1<<<256, 256, 0, stream>>>(counts, partial, N, SCAN_CHUNK);
    k_scan2<<<1, 256, 0, stream>>>(partial);
    k_scan3<<<256, 256, 0, stream>>>(counts, partial, rowptr, N, SCAN_CHUNK);
    k_fill_csr<<<(E + N + 255) / 256, 256, 0, stream>>>(ei, rowptr, fill, csr_src, csr_dst, csr_eid, E, N);
    k_loop_attr<<<(N * ED + 255) / 256, 256, 0, stream>>>(ea, rowptr, csr_eid, loop_attr, N, E);

    dim3 g1((N + GT - 1) / GT, H1 / GT);
    k_gemm_xwt<<<g1, 256, 0, stream>>>(x, Wl1, bl1, xl1, N, ND, H1);
    k_gemm_xwt<<<g1, 256, 0, stream>>>(x, Wr1, br1, xr1, N, ND, H1);

    k_logits1<<<2048, 256, 0, stream>>>(xl1, xr1, ea, loop_attr, We1, at1,
                                        csr_src, csr_dst, csr_eid, logit, ET, E);
    k_agg1<<<N, 256, 0, stream>>>(xl1, logit, rowptr, csr_src, bi1, h1);

    dim3 g2((N + GT - 1) / GT, 1);
    k_gemm_xwt<<<g2, 256, 0, stream>>>(h1, Wl2, bl2, xl2, N, H1, H2);
    k_gemm_xwt<<<g2, 256, 0, stream>>>(h1, Wr2, br2, xr2, N, H1, H2);

    k_logits2<<<1024, 256, 0, stream>>>(xl2, xr2, ea, loop_attr, We2, at2,
                                        csr_src, csr_dst, csr_eid, logit, ET, E);
    k_agg2<<<(N + 7) / 8, 256, 0, stream>>>(xl2, logit, rowptr, csr_src, bi2, h2, N);

    k_mean<<<128, 256, 0, stream>>>(h2, out, N * H2, 1.0f / (float)N);
}

// Round 3
// 989.587 us; speedup vs baseline: 1.4004x; 1.4004x over previous
//
#include <hip/hip_runtime.h>
#include <math.h>

#define N_NODES 50000
#define N_EDGES 800000
#define ND 128
#define ED 16
#define H1 256
#define H2 32
#define NEG_SLOPE 0.2f

// ---------------------------------------------------------------- degree counts
__global__ void k_deg(const int* __restrict__ ei, int* __restrict__ counts, int E) {
    int e = blockIdx.x * blockDim.x + threadIdx.x;
    if (e < E) atomicAdd(&counts[ei[E + e]], 1);
}

// ---------------------------------------------------------------- 3-phase scan -> rowptr (+1 self loop per node)
__global__ void k_scan1(const int* __restrict__ counts, int* __restrict__ partial, int n, int chunk) {
    __shared__ int sh[256];
    int beg = blockIdx.x * chunk, end = min(beg + chunk, n);
    int sum = 0;
    for (int i = beg + threadIdx.x; i < end; i += 256) sum += counts[i] + 1;
    sh[threadIdx.x] = sum;
    __syncthreads();
    for (int off = 128; off; off >>= 1) {
        if (threadIdx.x < off) sh[threadIdx.x] += sh[threadIdx.x + off];
        __syncthreads();
    }
    if (threadIdx.x == 0) partial[blockIdx.x] = sh[0];
}
__global__ void k_scan2(int* __restrict__ partial) {
    __shared__ int sh[256];
    int v = partial[threadIdx.x];
    sh[threadIdx.x] = v;
    __syncthreads();
    for (int off = 1; off < 256; off <<= 1) {
        int t = (threadIdx.x >= off) ? sh[threadIdx.x - off] : 0;
        __syncthreads();
        sh[threadIdx.x] += t;
        __syncthreads();
    }
    partial[threadIdx.x] = sh[threadIdx.x] - v;
}
__global__ void k_scan3(const int* __restrict__ counts, const int* __restrict__ partial,
                        int* __restrict__ rowptr, int n, int chunk) {
    __shared__ int sh[256];
    int beg = blockIdx.x * chunk, end = min(beg + chunk, n);
    int run = partial[blockIdx.x];
    for (int base = beg; base < end; base += 256) {
        int i = base + threadIdx.x;
        int v = (i < end) ? counts[i] + 1 : 0;
        sh[threadIdx.x] = v;
        __syncthreads();
        for (int off = 1; off < 256; off <<= 1) {
            int t = (threadIdx.x >= off) ? sh[threadIdx.x - off] : 0;
            __syncthreads();
            sh[threadIdx.x] += t;
            __syncthreads();
        }
        if (i < end) rowptr[i + 1] = run + sh[threadIdx.x];
        __syncthreads();
        run += sh[255];
        __syncthreads();
    }
    if (blockIdx.x == 0 && threadIdx.x == 0) rowptr[0] = 0;
}

// ---------------------------------------------------------------- fill CSR; self loop in last slot
__global__ void k_fill_csr(const int* __restrict__ ei, const int* __restrict__ rowptr,
                           int* __restrict__ fill, int* __restrict__ csr_src,
                           int* __restrict__ csr_eid, int E, int n) {
    int idx = blockIdx.x * blockDim.x + threadIdx.x;
    if (idx < E) {
        int dst = ei[E + idx];
        int slot = rowptr[dst] + atomicAdd(&fill[dst], 1);
        csr_src[slot] = ei[idx];
        csr_eid[slot] = idx;
    } else if (idx < E + n) {
        int i = idx - E;
        int slot = rowptr[i + 1] - 1;
        csr_src[slot] = i;
        csr_eid[slot] = E + i;
    }
}

// ---------------------------------------------------------------- loop_attr from CSR (no atomics)
__global__ void k_loop_attr(const float* __restrict__ ea, const int* __restrict__ rowptr,
                            const int* __restrict__ csr_eid, float* __restrict__ loop_attr, int n, int E) {
    int idx = blockIdx.x * blockDim.x + threadIdx.x;
    if (idx >= n * ED) return;
    int node = idx >> 4, d = idx & 15;
    int beg = rowptr[node], end = rowptr[node + 1] - 1;  // exclude self-loop slot
    float sum = 0.f;
    for (int j = beg; j < end; ++j) sum += ea[(size_t)csr_eid[j] * ED + d];
    int cnt = end - beg;
    loop_attr[idx] = sum / (float)(cnt > 0 ? cnt : 1);
}

// ---------------------------------------------------------------- dual GEMM: Ya|Yb[r][c] = X[r][:] . W{a|b}[c][:] + b
// columns [0,C) -> Wa/ba/Ya, [C,2C) -> Wb/bb/Yb. gridDim.y = 2C/64.
#define GT 64
#define GK 32
#define LDP 68
__global__ __launch_bounds__(256) void k_gemm_dual(const float* __restrict__ X,
                                                   const float* __restrict__ Wa,
                                                   const float* __restrict__ ba,
                                                   float* __restrict__ Ya,
                                                   const float* __restrict__ Wb,
                                                   const float* __restrict__ bb,
                                                   float* __restrict__ Yb,
                                                   int n, int K, int C) {
    __shared__ float xs[GK][LDP];
    __shared__ float ws[GK][LDP];
    int tid = threadIdx.x;
    int tx = tid & 15, ty = tid >> 4;
    int row0 = blockIdx.x * GT, col0 = blockIdx.y * GT;
    float acc[4][4] = {};
    for (int k0 = 0; k0 < K; k0 += GK) {
        #pragma unroll
        for (int l = 0; l < 2; ++l) {
            int t = l * 256 + tid;
            int r = t >> 3, c4 = t & 7;
            int gr = row0 + r;
            float4 xv = {0.f, 0.f, 0.f, 0.f};
            if (gr < n) xv = *(const float4*)(X + (size_t)gr * K + k0 + c4 * 4);
            xs[c4 * 4 + 0][r] = xv.x; xs[c4 * 4 + 1][r] = xv.y;
            xs[c4 * 4 + 2][r] = xv.z; xs[c4 * 4 + 3][r] = xv.w;
            int gc = col0 + r;
            const float* wrow = (gc < C) ? Wa + (size_t)gc * K : Wb + (size_t)(gc - C) * K;
            float4 wv = *(const float4*)(wrow + k0 + c4 * 4);
            ws[c4 * 4 + 0][r] = wv.x; ws[c4 * 4 + 1][r] = wv.y;
            ws[c4 * 4 + 2][r] = wv.z; ws[c4 * 4 + 3][r] = wv.w;
        }
        __syncthreads();
        #pragma unroll
        for (int kk = 0; kk < GK; ++kk) {
            float4 a = *(const float4*)&xs[kk][ty * 4];
            float4 b = *(const float4*)&ws[kk][tx * 4];
            const float* af = (const float*)&a;
            const float* bf = (const float*)&b;
            #pragma unroll
            for (int i = 0; i < 4; ++i)
                #pragma unroll
                for (int j = 0; j < 4; ++j) acc[i][j] += af[i] * bf[j];
        }
        __syncthreads();
    }
    #pragma unroll
    for (int i = 0; i < 4; ++i) {
        int r = row0 + ty * 4 + i;
        if (r >= n) continue;
        #pragma unroll
        for (int j = 0; j < 4; ++j) {
            int c = col0 + tx * 4 + j;
            if (c < C) Ya[(size_t)r * C + c] = acc[i][j] + ba[c];
            else       Yb[(size_t)r * C + (c - C)] = acc[i][j] + bb[c - C];
        }
    }
}

// ---------------------------------------------------------------- layer-1 fused GAT: one wave per node, no barriers
__global__ __launch_bounds__(256) void k_gat1(const float* __restrict__ xl,
                                              const float* __restrict__ xr,
                                              const float* __restrict__ edge_attr,
                                              const float* __restrict__ loop_attr,
                                              const float* __restrict__ We,
                                              const float* __restrict__ att,
                                              const float* __restrict__ bias,
                                              const int* __restrict__ rowptr,
                                              const int* __restrict__ csr_src,
                                              const int* __restrict__ csr_eid,
                                              float* __restrict__ out, int n, int E) {
    int lane = threadIdx.x & 63;
    int wave = (blockIdx.x * blockDim.x + threadIdx.x) >> 6;
    int nwaves = (gridDim.x * blockDim.x) >> 6;
    float4 w[4][4];
    #pragma unroll
    for (int r = 0; r < 4; ++r)
        #pragma unroll
        for (int q = 0; q < 4; ++q) w[r][q] = ((const float4*)We)[(lane * 4 + r) * 4 + q];
    float4 attv = ((const float4*)att)[lane];
    float4 bv = ((const float4*)bias)[lane];

    for (int node = wave; node < n; node += nwaves) {
        float4 xrv = *(const float4*)(xr + (size_t)node * H1 + lane * 4);
        int beg = rowptr[node], end = rowptr[node + 1];
        float denom = 0.f;
        float4 acc = {0.f, 0.f, 0.f, 0.f};
        #pragma unroll 2
        for (int j = beg; j < end; ++j) {
            int s = csr_src[j];
            int e = csr_eid[j];
            const float* eap = (e < E) ? edge_attr + (size_t)e * ED
                                       : loop_attr + (size_t)(e - E) * ED;
            float4 xlv = *(const float4*)(xl + (size_t)s * H1 + lane * 4);
            float4 ea0 = ((const float4*)eap)[0];
            float4 ea1 = ((const float4*)eap)[1];
            float4 ea2 = ((const float4*)eap)[2];
            float4 ea3 = ((const float4*)eap)[3];
            float p = 0.f;
            #pragma unroll
            for (int r = 0; r < 4; ++r) {
                float we = w[r][0].x * ea0.x + w[r][0].y * ea0.y + w[r][0].z * ea0.z + w[r][0].w * ea0.w
                         + w[r][1].x * ea1.x + w[r][1].y * ea1.y + w[r][1].z * ea1.z + w[r][1].w * ea1.w
                         + w[r][2].x * ea2.x + w[r][2].y * ea2.y + w[r][2].z * ea2.z + w[r][2].w * ea2.w
                         + w[r][3].x * ea3.x + w[r][3].y * ea3.y + w[r][3].z * ea3.z + w[r][3].w * ea3.w;
                float t = ((const float*)&xlv)[r] + ((const float*)&xrv)[r] + we;
                t = (t > 0.f) ? t : NEG_SLOPE * t;
                p += ((const float*)&attv)[r] * t;
            }
            #pragma unroll
            for (int off = 32; off >= 1; off >>= 1) p += __shfl_xor(p, off);
            // logits bounded (|p| ~ few): exp without max-shift == reference softmax
            float pe = __expf(p);
            denom += pe;
            acc.x += pe * xlv.x; acc.y += pe * xlv.y;
            acc.z += pe * xlv.z; acc.w += pe * xlv.w;
        }
        float inv = 1.f / denom;
        float4 o;
        o.x = acc.x * inv + bv.x; o.y = acc.y * inv + bv.y;
        o.z = acc.z * inv + bv.z; o.w = acc.w * inv + bv.w;
        *(float4*)(out + (size_t)node * H1 + lane * 4) = o;
    }
}

// ---------------------------------------------------------------- layer-2 fused GAT: half-wave (32 lanes) per node
__global__ __launch_bounds__(256) void k_gat2(const float* __restrict__ xl,
                                              const float* __restrict__ xr,
                                              const float* __restrict__ edge_attr,
                                              const float* __restrict__ loop_attr,
                                              const float* __restrict__ We,
                                              const float* __restrict__ att,
                                              const float* __restrict__ bias,
                                              const int* __restrict__ rowptr,
                                              const int* __restrict__ csr_src,
                                              const int* __restrict__ csr_eid,
                                              float* __restrict__ out, int n, int E) {
    int tid = threadIdx.x;
    int c = tid & 31;
    int half = (blockIdx.x * blockDim.x + tid) >> 5;
    int nhalf = (gridDim.x * blockDim.x) >> 5;
    float4 w0 = ((const float4*)We)[c * 4 + 0];
    float4 w1 = ((const float4*)We)[c * 4 + 1];
    float4 w2 = ((const float4*)We)[c * 4 + 2];
    float4 w3 = ((const float4*)We)[c * 4 + 3];
    float attc = att[c], bc = bias[c];

    for (int node = half; node < n; node += nhalf) {
        float xrc = xr[(size_t)node * H2 + c];
        int beg = rowptr[node], end = rowptr[node + 1];
        float denom = 0.f, acc = 0.f;
        #pragma unroll 2
        for (int j = beg; j < end; ++j) {
            int s = csr_src[j];
            int e = csr_eid[j];
            const float* eap = (e < E) ? edge_attr + (size_t)e * ED
                                       : loop_attr + (size_t)(e - E) * ED;
            float xlv = xl[(size_t)s * H2 + c];
            float4 ea0 = ((const float4*)eap)[0];
            float4 ea1 = ((const float4*)eap)[1];
            float4 ea2 = ((const float4*)eap)[2];
            float4 ea3 = ((const float4*)eap)[3];
            float we = w0.x * ea0.x + w0.y * ea0.y + w0.z * ea0.z + w0.w * ea0.w
                     + w1.x * ea1.x + w1.y * ea1.y + w1.z * ea1.z + w1.w * ea1.w
                     + w2.x * ea2.x + w2.y * ea2.y + w2.z * ea2.z + w2.w * ea2.w
                     + w3.x * ea3.x + w3.y * ea3.y + w3.z * ea3.z + w3.w * ea3.w;
            float t = xlv + xrc + we;
            t = (t > 0.f) ? t : NEG_SLOPE * t;
            float p = attc * t;
            #pragma unroll
            for (int off = 16; off >= 1; off >>= 1) p += __shfl_xor(p, off);
            float pe = __expf(p);
            denom += pe;
            acc += pe * xlv;
        }
        out[(size_t)node * H2 + c] = acc / denom + bc;
    }
}

// ---------------------------------------------------------------- mean over nodes
__global__ __launch_bounds__(256) void k_mean(const float* __restrict__ h2,
                                              float* __restrict__ out, int total, float invN) {
    __shared__ float red[H2];
    int tid = threadIdx.x;
    if (tid < H2) red[tid] = 0.f;
    __syncthreads();
    float part = 0.f;
    for (int idx = blockIdx.x * blockDim.x + tid; idx < total; idx += gridDim.x * blockDim.x)
        part += h2[idx];
    atomicAdd(&red[tid & 31], part);
    __syncthreads();
    if (tid < H2) atomicAdd(&out[tid], red[tid] * invN);
}

// ----------------------------------------------------------------
extern "C" void kernel_launch(void* const* d_in, const int* in_sizes, int n_in,
                              void* d_out, int out_size, void* d_ws, size_t ws_size,
                              hipStream_t stream) {
    const float* x   = (const float*)d_in[0];
    const int*   ei  = (const int*)d_in[1];
    const float* ea  = (const float*)d_in[2];
    const float* Wl1 = (const float*)d_in[3];
    const float* bl1 = (const float*)d_in[4];
    const float* Wr1 = (const float*)d_in[5];
    const float* br1 = (const float*)d_in[6];
    const float* We1 = (const float*)d_in[7];
    const float* at1 = (const float*)d_in[8];
    const float* bi1 = (const float*)d_in[9];
    const float* Wl2 = (const float*)d_in[10];
    const float* bl2 = (const float*)d_in[11];
    const float* Wr2 = (const float*)d_in[12];
    const float* br2 = (const float*)d_in[13];
    const float* We2 = (const float*)d_in[14];
    const float* at2 = (const float*)d_in[15];
    const float* bi2 = (const float*)d_in[16];
    float* out = (float*)d_out;

    const int N = N_NODES, E = N_EDGES, ET = N_EDGES + N_NODES;
    const int SCAN_CHUNK = (N + 255) / 256;

    size_t off = 0;
    auto carve = [&](size_t bytes) {
        void* p = (char*)d_ws + off;
        off += (bytes + 255) & ~(size_t)255;
        return p;
    };
    int*   counts    = (int*)carve((size_t)N * 4);
    int*   fill      = (int*)carve((size_t)N * 4);
    int*   rowptr    = (int*)carve((size_t)(N + 1) * 4);
    int*   partial   = (int*)carve(256 * 4);
    float* loop_attr = (float*)carve((size_t)N * ED * 4);
    int*   csr_src   = (int*)carve((size_t)ET * 4);
    int*   csr_eid   = (int*)carve((size_t)ET * 4);
    float* xl1       = (float*)carve((size_t)N * H1 * 4);
    float* xr1       = (float*)carve((size_t)N * H1 * 4);
    float* h1        = (float*)carve((size_t)N * H1 * 4);
    // layer-2 buffers alias xr1 (free after k_gat1)
    float* xl2 = xr1;
    float* xr2 = xr1 + (size_t)N * H2;
    float* h2  = xr1 + 2 * (size_t)N * H2;

    hipMemsetAsync(counts, 0, (size_t)N * 4, stream);
    hipMemsetAsync(fill, 0, (size_t)N * 4, stream);
    hipMemsetAsync(out, 0, (size_t)H2 * 4, stream);

    k_deg<<<(E + 255) / 256, 256, 0, stream>>>(ei, counts, E);
    k_scan1<<<256, 256, 0, stream>>>(counts, partial, N, SCAN_CHUNK);
    k_scan2<<<1, 256, 0, stream>>>(partial);
    k_scan3<<<256, 256, 0, stream>>>(counts, partial, rowptr, N, SCAN_CHUNK);
    k_fill_csr<<<(E + N + 255) / 256, 256, 0, stream>>>(ei, rowptr, fill, csr_src, csr_eid, E, N);
    k_loop_attr<<<(N * ED + 255) / 256, 256, 0, stream>>>(ea, rowptr, csr_eid, loop_attr, N, E);

    // layer 1
    k_gemm_dual<<<dim3((N + GT - 1) / GT, (2 * H1) / GT), 256, 0, stream>>>(
        x, Wl1, bl1, xl1, Wr1, br1, xr1, N, ND, H1);
    k_gat1<<<2048, 256, 0, stream>>>(xl1, xr1, ea, loop_attr, We1, at1, bi1,
                                     rowptr, csr_src, csr_eid, h1, N, E);

    // layer 2
    k_gemm_dual<<<dim3((N + GT - 1) / GT, (2 * H2) / GT), 256, 0, stream>>>(
        h1, Wl2, bl2, xl2, Wr2, br2, xr2, N, H1, H2);
    k_gat2<<<512, 256, 0, stream>>>(xl2, xr2, ea, loop_attr, We2, at2, bi2,
                                    rowptr, csr_src, csr_eid, h2, N, E);

    k_mean<<<128, 256, 0, stream>>>(h2, out, N * H2, 1.0f / (float)N);
}

// Round 4
// 499.949 us; speedup vs baseline: 2.7720x; 1.9794x over previous
//
#include <hip/hip_runtime.h>
#include <math.h>

#define N_NODES 50000
#define N_EDGES 800000
#define ND 128
#define ED 16
#define H1 256
#define H2 32
#define NEG_SLOPE 0.2f

typedef _Float16 half2v __attribute__((ext_vector_type(2)));

#if defined(__has_builtin)
#if __has_builtin(__builtin_amdgcn_fdot2)
#define FDOT2(a, b, c) __builtin_amdgcn_fdot2((a), (b), (c), false)
#endif
#endif
#ifndef FDOT2
#define FDOT2(a, b, c) ((float)(a).x * (float)(b).x + (float)(a).y * (float)(b).y + (c))
#endif

// ---------------------------------------------------------------- degree counts
__global__ void k_deg(const int* __restrict__ ei, int* __restrict__ counts, int E) {
    int e = blockIdx.x * blockDim.x + threadIdx.x;
    if (e < E) atomicAdd(&counts[ei[E + e]], 1);
}

// ---------------------------------------------------------------- 3-phase scan -> rowptr (+1 self loop per node)
__global__ void k_scan1(const int* __restrict__ counts, int* __restrict__ partial, int n, int chunk) {
    __shared__ int sh[256];
    int beg = blockIdx.x * chunk, end = min(beg + chunk, n);
    int sum = 0;
    for (int i = beg + threadIdx.x; i < end; i += 256) sum += counts[i] + 1;
    sh[threadIdx.x] = sum;
    __syncthreads();
    for (int off = 128; off; off >>= 1) {
        if (threadIdx.x < off) sh[threadIdx.x] += sh[threadIdx.x + off];
        __syncthreads();
    }
    if (threadIdx.x == 0) partial[blockIdx.x] = sh[0];
}
__global__ void k_scan2(int* __restrict__ partial) {
    __shared__ int sh[256];
    int v = partial[threadIdx.x];
    sh[threadIdx.x] = v;
    __syncthreads();
    for (int off = 1; off < 256; off <<= 1) {
        int t = (threadIdx.x >= off) ? sh[threadIdx.x - off] : 0;
        __syncthreads();
        sh[threadIdx.x] += t;
        __syncthreads();
    }
    partial[threadIdx.x] = sh[threadIdx.x] - v;
}
__global__ void k_scan3(const int* __restrict__ counts, const int* __restrict__ partial,
                        int* __restrict__ rowptr, int n, int chunk) {
    __shared__ int sh[256];
    int beg = blockIdx.x * chunk, end = min(beg + chunk, n);
    int run = partial[blockIdx.x];
    for (int base = beg; base < end; base += 256) {
        int i = base + threadIdx.x;
        int v = (i < end) ? counts[i] + 1 : 0;
        sh[threadIdx.x] = v;
        __syncthreads();
        for (int off = 1; off < 256; off <<= 1) {
            int t = (threadIdx.x >= off) ? sh[threadIdx.x - off] : 0;
            __syncthreads();
            sh[threadIdx.x] += t;
            __syncthreads();
        }
        if (i < end) rowptr[i + 1] = run + sh[threadIdx.x];
        __syncthreads();
        run += sh[255];
        __syncthreads();
    }
    if (blockIdx.x == 0 && threadIdx.x == 0) rowptr[0] = 0;
}

// ---------------------------------------------------------------- fill CSR: src + ea rows (f16) in slot order
__global__ void k_fill_csr(const int* __restrict__ ei, const float* __restrict__ ea,
                           const int* __restrict__ rowptr, int* __restrict__ fill,
                           int* __restrict__ csr_src, _Float16* __restrict__ ea_h, int E, int n) {
    int idx = blockIdx.x * blockDim.x + threadIdx.x;
    if (idx < E) {
        int dst = ei[E + idx];
        int slot = rowptr[dst] + atomicAdd(&fill[dst], 1);
        csr_src[slot] = ei[idx];
        const float* srow = ea + (size_t)idx * ED;
        _Float16* drow = ea_h + (size_t)slot * ED;
        #pragma unroll
        for (int q = 0; q < 4; ++q) {
            float4 f = ((const float4*)srow)[q];
            drow[q * 4 + 0] = (_Float16)f.x;
            drow[q * 4 + 1] = (_Float16)f.y;
            drow[q * 4 + 2] = (_Float16)f.z;
            drow[q * 4 + 3] = (_Float16)f.w;
        }
    } else if (idx < E + n) {
        int i = idx - E;
        csr_src[rowptr[i + 1] - 1] = i;  // self loop in last slot
    }
}

// ---------------------------------------------------------------- self-loop attr row = mean of node's edge rows (in place)
__global__ void k_loop_mean(_Float16* __restrict__ ea_h, const int* __restrict__ rowptr, int n) {
    int idx = blockIdx.x * blockDim.x + threadIdx.x;
    if (idx >= n * ED) return;
    int node = idx >> 4, d = idx & 15;
    int beg = rowptr[node], last = rowptr[node + 1] - 1;
    float s = 0.f;
    for (int j = beg; j < last; ++j) s += (float)ea_h[(size_t)j * ED + d];
    int cnt = last - beg;
    ea_h[(size_t)last * ED + d] = (_Float16)(s / (float)(cnt > 0 ? cnt : 1));
}

// ---------------------------------------------------------------- pack f32 -> f16
__global__ void k_pack_half(const float* __restrict__ src, _Float16* __restrict__ dst, int total) {
    int i = blockIdx.x * blockDim.x + threadIdx.x;
    if (i < total) dst[i] = (_Float16)src[i];
}

// ---------------------------------------------------------------- dual GEMM: Ya|Yb[r][c] = X[r][:] . W{a|b}[c][:] + b
#define GT 64
#define GK 32
#define LDP 68
__global__ __launch_bounds__(256) void k_gemm_dual(const float* __restrict__ X,
                                                   const float* __restrict__ Wa,
                                                   const float* __restrict__ ba,
                                                   float* __restrict__ Ya,
                                                   const float* __restrict__ Wb,
                                                   const float* __restrict__ bb,
                                                   float* __restrict__ Yb,
                                                   int n, int K, int C) {
    __shared__ float xs[GK][LDP];
    __shared__ float ws[GK][LDP];
    int tid = threadIdx.x;
    int tx = tid & 15, ty = tid >> 4;
    int row0 = blockIdx.x * GT, col0 = blockIdx.y * GT;
    float acc[4][4] = {};
    for (int k0 = 0; k0 < K; k0 += GK) {
        #pragma unroll
        for (int l = 0; l < 2; ++l) {
            int t = l * 256 + tid;
            int r = t >> 3, c4 = t & 7;
            int gr = row0 + r;
            float4 xv = {0.f, 0.f, 0.f, 0.f};
            if (gr < n) xv = *(const float4*)(X + (size_t)gr * K + k0 + c4 * 4);
            xs[c4 * 4 + 0][r] = xv.x; xs[c4 * 4 + 1][r] = xv.y;
            xs[c4 * 4 + 2][r] = xv.z; xs[c4 * 4 + 3][r] = xv.w;
            int gc = col0 + r;
            const float* wrow = (gc < C) ? Wa + (size_t)gc * K : Wb + (size_t)(gc - C) * K;
            float4 wv = *(const float4*)(wrow + k0 + c4 * 4);
            ws[c4 * 4 + 0][r] = wv.x; ws[c4 * 4 + 1][r] = wv.y;
            ws[c4 * 4 + 2][r] = wv.z; ws[c4 * 4 + 3][r] = wv.w;
        }
        __syncthreads();
        #pragma unroll
        for (int kk = 0; kk < GK; ++kk) {
            float4 a = *(const float4*)&xs[kk][ty * 4];
            float4 b = *(const float4*)&ws[kk][tx * 4];
            const float* af = (const float*)&a;
            const float* bf = (const float*)&b;
            #pragma unroll
            for (int i = 0; i < 4; ++i)
                #pragma unroll
                for (int j = 0; j < 4; ++j) acc[i][j] += af[i] * bf[j];
        }
        __syncthreads();
    }
    #pragma unroll
    for (int i = 0; i < 4; ++i) {
        int r = row0 + ty * 4 + i;
        if (r >= n) continue;
        #pragma unroll
        for (int j = 0; j < 4; ++j) {
            int c = col0 + tx * 4 + j;
            if (c < C) Ya[(size_t)r * C + c] = acc[i][j] + ba[c];
            else       Yb[(size_t)r * C + (c - C)] = acc[i][j] + bb[c - C];
        }
    }
}

// ---------------------------------------------------------------- layer-1 fused GAT: wave/node, f16 dots, 2-edge unroll
__global__ __launch_bounds__(256) void k_gat1(const float* __restrict__ xl,
                                              const float* __restrict__ xr,
                                              const _Float16* __restrict__ ea_h,
                                              const _Float16* __restrict__ We_h,
                                              const float* __restrict__ att,
                                              const float* __restrict__ bias,
                                              const int* __restrict__ rowptr,
                                              const int* __restrict__ csr_src,
                                              float* __restrict__ out, int n) {
    int lane = threadIdx.x & 63;
    int wave = (blockIdx.x * blockDim.x + threadIdx.x) >> 6;
    int nwaves = (gridDim.x * blockDim.x) >> 6;
    const half2v* Wp = (const half2v*)We_h;
    half2v w[4][8];
    #pragma unroll
    for (int r = 0; r < 4; ++r)
        #pragma unroll
        for (int q = 0; q < 8; ++q) w[r][q] = Wp[(lane * 4 + r) * 8 + q];
    float4 attv = ((const float4*)att)[lane];
    float4 bv = ((const float4*)bias)[lane];

    for (int node = wave; node < n; node += nwaves) {
        float4 xrv = *(const float4*)(xr + (size_t)node * H1 + lane * 4);
        int beg = rowptr[node], end = rowptr[node + 1];
        float denom = 0.f;
        float4 acc = {0.f, 0.f, 0.f, 0.f};
        int j = beg;
        for (; j + 1 < end; j += 2) {
            int sA = csr_src[j], sB = csr_src[j + 1];
            const half2v* eA = (const half2v*)(ea_h + (size_t)j * ED);
            const half2v* eB = (const half2v*)(ea_h + (size_t)(j + 1) * ED);
            half2v a0 = eA[0], a1 = eA[1], a2 = eA[2], a3 = eA[3];
            half2v a4 = eA[4], a5 = eA[5], a6 = eA[6], a7 = eA[7];
            half2v b0 = eB[0], b1 = eB[1], b2 = eB[2], b3 = eB[3];
            half2v b4 = eB[4], b5 = eB[5], b6 = eB[6], b7 = eB[7];
            float4 xlA = *(const float4*)(xl + (size_t)sA * H1 + lane * 4);
            float4 xlB = *(const float4*)(xl + (size_t)sB * H1 + lane * 4);
            float pA = 0.f, pB = 0.f;
            #pragma unroll
            for (int r = 0; r < 4; ++r) {
                float weA = 0.f, weB = 0.f;
                weA = FDOT2(w[r][0], a0, weA); weB = FDOT2(w[r][0], b0, weB);
                weA = FDOT2(w[r][1], a1, weA); weB = FDOT2(w[r][1], b1, weB);
                weA = FDOT2(w[r][2], a2, weA); weB = FDOT2(w[r][2], b2, weB);
                weA = FDOT2(w[r][3], a3, weA); weB = FDOT2(w[r][3], b3, weB);
                weA = FDOT2(w[r][4], a4, weA); weB = FDOT2(w[r][4], b4, weB);
                weA = FDOT2(w[r][5], a5, weA); weB = FDOT2(w[r][5], b5, weB);
                weA = FDOT2(w[r][6], a6, weA); weB = FDOT2(w[r][6], b6, weB);
                weA = FDOT2(w[r][7], a7, weA); weB = FDOT2(w[r][7], b7, weB);
                float tA = ((const float*)&xlA)[r] + ((const float*)&xrv)[r] + weA;
                float tB = ((const float*)&xlB)[r] + ((const float*)&xrv)[r] + weB;
                tA = (tA > 0.f) ? tA : NEG_SLOPE * tA;
                tB = (tB > 0.f) ? tB : NEG_SLOPE * tB;
                pA += ((const float*)&attv)[r] * tA;
                pB += ((const float*)&attv)[r] * tB;
            }
            #pragma unroll
            for (int off = 32; off >= 1; off >>= 1) {
                pA += __shfl_xor(pA, off);
                pB += __shfl_xor(pB, off);
            }
            float peA = __expf(pA), peB = __expf(pB);
            denom += peA + peB;
            acc.x += peA * xlA.x + peB * xlB.x;
            acc.y += peA * xlA.y + peB * xlB.y;
            acc.z += peA * xlA.z + peB * xlB.z;
            acc.w += peA * xlA.w + peB * xlB.w;
        }
        if (j < end) {
            int sA = csr_src[j];
            const half2v* eA = (const half2v*)(ea_h + (size_t)j * ED);
            half2v a0 = eA[0], a1 = eA[1], a2 = eA[2], a3 = eA[3];
            half2v a4 = eA[4], a5 = eA[5], a6 = eA[6], a7 = eA[7];
            float4 xlA = *(const float4*)(xl + (size_t)sA * H1 + lane * 4);
            float pA = 0.f;
            #pragma unroll
            for (int r = 0; r < 4; ++r) {
                float weA = 0.f;
                weA = FDOT2(w[r][0], a0, weA);
                weA = FDOT2(w[r][1], a1, weA);
                weA = FDOT2(w[r][2], a2, weA);
                weA = FDOT2(w[r][3], a3, weA);
                weA = FDOT2(w[r][4], a4, weA);
                weA = FDOT2(w[r][5], a5, weA);
                weA = FDOT2(w[r][6], a6, weA);
                weA = FDOT2(w[r][7], a7, weA);
                float tA = ((const float*)&xlA)[r] + ((const float*)&xrv)[r] + weA;
                tA = (tA > 0.f) ? tA : NEG_SLOPE * tA;
                pA += ((const float*)&attv)[r] * tA;
            }
            #pragma unroll
            for (int off = 32; off >= 1; off >>= 1) pA += __shfl_xor(pA, off);
            float peA = __expf(pA);
            denom += peA;
            acc.x += peA * xlA.x; acc.y += peA * xlA.y;
            acc.z += peA * xlA.z; acc.w += peA * xlA.w;
        }
        float inv = 1.f / denom;
        float4 o;
        o.x = acc.x * inv + bv.x; o.y = acc.y * inv + bv.y;
        o.z = acc.z * inv + bv.z; o.w = acc.w * inv + bv.w;
        *(float4*)(out + (size_t)node * H1 + lane * 4) = o;
    }
}

// ---------------------------------------------------------------- layer-2 fused GAT: 32-lane group/node, 2-edge unroll
__global__ __launch_bounds__(256) void k_gat2(const float* __restrict__ xl,
                                              const float* __restrict__ xr,
                                              const _Float16* __restrict__ ea_h,
                                              const _Float16* __restrict__ We_h,
                                              const float* __restrict__ att,
                                              const float* __restrict__ bias,
                                              const int* __restrict__ rowptr,
                                              const int* __restrict__ csr_src,
                                              float* __restrict__ out, int n) {
    int tid = threadIdx.x;
    int c = tid & 31;
    int grp = (blockIdx.x * blockDim.x + tid) >> 5;
    int ngrp = (gridDim.x * blockDim.x) >> 5;
    const half2v* Wp = (const half2v*)We_h;
    half2v w0 = Wp[c * 8 + 0], w1 = Wp[c * 8 + 1], w2 = Wp[c * 8 + 2], w3 = Wp[c * 8 + 3];
    half2v w4 = Wp[c * 8 + 4], w5 = Wp[c * 8 + 5], w6 = Wp[c * 8 + 6], w7 = Wp[c * 8 + 7];
    float attc = att[c], bc = bias[c];

    for (int node = grp; node < n; node += ngrp) {
        float xrc = xr[(size_t)node * H2 + c];
        int beg = rowptr[node], end = rowptr[node + 1];
        float denom = 0.f, acc = 0.f;
        int j = beg;
        for (; j + 1 < end; j += 2) {
            int sA = csr_src[j], sB = csr_src[j + 1];
            const half2v* eA = (const half2v*)(ea_h + (size_t)j * ED);
            const half2v* eB = (const half2v*)(ea_h + (size_t)(j + 1) * ED);
            half2v a0 = eA[0], a1 = eA[1], a2 = eA[2], a3 = eA[3];
            half2v a4 = eA[4], a5 = eA[5], a6 = eA[6], a7 = eA[7];
            half2v b0 = eB[0], b1 = eB[1], b2 = eB[2], b3 = eB[3];
            half2v b4 = eB[4], b5 = eB[5], b6 = eB[6], b7 = eB[7];
            float xlA = xl[(size_t)sA * H2 + c];
            float xlB = xl[(size_t)sB * H2 + c];
            float weA = 0.f, weB = 0.f;
            weA = FDOT2(w0, a0, weA); weB = FDOT2(w0, b0, weB);
            weA = FDOT2(w1, a1, weA); weB = FDOT2(w1, b1, weB);
            weA = FDOT2(w2, a2, weA); weB = FDOT2(w2, b2, weB);
            weA = FDOT2(w3, a3, weA); weB = FDOT2(w3, b3, weB);
            weA = FDOT2(w4, a4, weA); weB = FDOT2(w4, b4, weB);
            weA = FDOT2(w5, a5, weA); weB = FDOT2(w5, b5, weB);
            weA = FDOT2(w6, a6, weA); weB = FDOT2(w6, b6, weB);
            weA = FDOT2(w7, a7, weA); weB = FDOT2(w7, b7, weB);
            float tA = xlA + xrc + weA;
            float tB = xlB + xrc + weB;
            tA = (tA > 0.f) ? tA : NEG_SLOPE * tA;
            tB = (tB > 0.f) ? tB : NEG_SLOPE * tB;
            float pA = attc * tA, pB = attc * tB;
            #pragma unroll
            for (int off = 16; off >= 1; off >>= 1) {
                pA += __shfl_xor(pA, off);
                pB += __shfl_xor(pB, off);
            }
            float peA = __expf(pA), peB = __expf(pB);
            denom += peA + peB;
            acc += peA * xlA + peB * xlB;
        }
        if (j < end) {
            int sA = csr_src[j];
            const half2v* eA = (const half2v*)(ea_h + (size_t)j * ED);
            half2v a0 = eA[0], a1 = eA[1], a2 = eA[2], a3 = eA[3];
            half2v a4 = eA[4], a5 = eA[5], a6 = eA[6], a7 = eA[7];
            float xlA = xl[(size_t)sA * H2 + c];
            float weA = 0.f;
            weA = FDOT2(w0, a0, weA);
            weA = FDOT2(w1, a1, weA);
            weA = FDOT2(w2, a2, weA);
            weA = FDOT2(w3, a3, weA);
            weA = FDOT2(w4, a4, weA);
            weA = FDOT2(w5, a5, weA);
            weA = FDOT2(w6, a6, weA);
            weA = FDOT2(w7, a7, weA);
            float tA = xlA + xrc + weA;
            tA = (tA > 0.f) ? tA : NEG_SLOPE * tA;
            float pA = attc * tA;
            #pragma unroll
            for (int off = 16; off >= 1; off >>= 1) pA += __shfl_xor(pA, off);
            float peA = __expf(pA);
            denom += peA;
            acc += peA * xlA;
        }
        out[(size_t)node * H2 + c] = acc / denom + bc;
    }
}

// ---------------------------------------------------------------- mean over nodes
__global__ __launch_bounds__(256) void k_mean(const float* __restrict__ h2,
                                              float* __restrict__ out, int total, float invN) {
    __shared__ float red[H2];
    int tid = threadIdx.x;
    if (tid < H2) red[tid] = 0.f;
    __syncthreads();
    float part = 0.f;
    for (int idx = blockIdx.x * blockDim.x + tid; idx < total; idx += gridDim.x * blockDim.x)
        part += h2[idx];
    atomicAdd(&red[tid & 31], part);
    __syncthreads();
    if (tid < H2) atomicAdd(&out[tid], red[tid] * invN);
}

// ----------------------------------------------------------------
extern "C" void kernel_launch(void* const* d_in, const int* in_sizes, int n_in,
                              void* d_out, int out_size, void* d_ws, size_t ws_size,
                              hipStream_t stream) {
    const float* x   = (const float*)d_in[0];
    const int*   ei  = (const int*)d_in[1];
    const float* ea  = (const float*)d_in[2];
    const float* Wl1 = (const float*)d_in[3];
    const float* bl1 = (const float*)d_in[4];
    const float* Wr1 = (const float*)d_in[5];
    const float* br1 = (const float*)d_in[6];
    const float* We1 = (const float*)d_in[7];
    const float* at1 = (const float*)d_in[8];
    const float* bi1 = (const float*)d_in[9];
    const float* Wl2 = (const float*)d_in[10];
    const float* bl2 = (const float*)d_in[11];
    const float* Wr2 = (const float*)d_in[12];
    const float* br2 = (const float*)d_in[13];
    const float* We2 = (const float*)d_in[14];
    const float* at2 = (const float*)d_in[15];
    const float* bi2 = (const float*)d_in[16];
    float* out = (float*)d_out;

    const int N = N_NODES, E = N_EDGES, ET = N_EDGES + N_NODES;
    const int SCAN_CHUNK = (N + 255) / 256;

    size_t off = 0;
    auto carve = [&](size_t bytes) {
        void* p = (char*)d_ws + off;
        off += (bytes + 255) & ~(size_t)255;
        return p;
    };
    int*      counts  = (int*)carve((size_t)N * 4);
    int*      fill    = (int*)carve((size_t)N * 4);
    int*      rowptr  = (int*)carve((size_t)(N + 1) * 4);
    int*      partial = (int*)carve(256 * 4);
    int*      csr_src = (int*)carve((size_t)ET * 4);
    _Float16* ea_h    = (_Float16*)carve((size_t)ET * ED * 2);
    _Float16* We1_h   = (_Float16*)carve((size_t)H1 * ED * 2);
    _Float16* We2_h   = (_Float16*)carve((size_t)H2 * ED * 2);
    float*    xl1     = (float*)carve((size_t)N * H1 * 4);
    float*    xr1     = (float*)carve((size_t)N * H1 * 4);
    float*    h1      = (float*)carve((size_t)N * H1 * 4);
    // layer-2 buffers alias xr1 (free after k_gat1)
    float* xl2 = xr1;
    float* xr2 = xr1 + (size_t)N * H2;
    float* h2  = xr1 + 2 * (size_t)N * H2;

    hipMemsetAsync(counts, 0, (size_t)N * 4, stream);
    hipMemsetAsync(fill, 0, (size_t)N * 4, stream);
    hipMemsetAsync(out, 0, (size_t)H2 * 4, stream);

    k_deg<<<(E + 255) / 256, 256, 0, stream>>>(ei, counts, E);
    k_scan1<<<256, 256, 0, stream>>>(counts, partial, N, SCAN_CHUNK);
    k_scan2<<<1, 256, 0, stream>>>(partial);
    k_scan3<<<256, 256, 0, stream>>>(counts, partial, rowptr, N, SCAN_CHUNK);
    k_fill_csr<<<(E + N + 255) / 256, 256, 0, stream>>>(ei, ea, rowptr, fill, csr_src, ea_h, E, N);
    k_loop_mean<<<(N * ED + 255) / 256, 256, 0, stream>>>(ea_h, rowptr, N);
    k_pack_half<<<(H1 * ED + 255) / 256, 256, 0, stream>>>(We1, We1_h, H1 * ED);
    k_pack_half<<<(H2 * ED + 255) / 256, 256, 0, stream>>>(We2, We2_h, H2 * ED);

    // layer 1
    k_gemm_dual<<<dim3((N + GT - 1) / GT, (2 * H1) / GT), 256, 0, stream>>>(
        x, Wl1, bl1, xl1, Wr1, br1, xr1, N, ND, H1);
    k_gat1<<<4096, 256, 0, stream>>>(xl1, xr1, ea_h, We1_h, at1, bi1,
                                     rowptr, csr_src, h1, N);

    // layer 2
    k_gemm_dual<<<dim3((N + GT - 1) / GT, (2 * H2) / GT), 256, 0, stream>>>(
        h1, Wl2, bl2, xl2, Wr2, br2, xr2, N, H1, H2);
    k_gat2<<<2048, 256, 0, stream>>>(xl2, xr2, ea_h, We2_h, at2, bi2,
                                     rowptr, csr_src, h2, N);

    k_mean<<<128, 256, 0, stream>>>(h2, out, N * H2, 1.0f / (float)N);
}